// Round 7
// baseline (175.598 us; speedup 1.0000x reference)
//
#include <hip/hip_runtime.h>

#define SCALE_EPS 1e-5f

typedef int v4i __attribute__((ext_vector_type(4)));
typedef int v16i __attribute__((ext_vector_type(16)));

static __device__ __forceinline__ void gll16(const void* g, void* l) {
  __builtin_amdgcn_global_load_lds(
      (const __attribute__((address_space(1))) unsigned int*)g,
      (__attribute__((address_space(3))) unsigned int*)l,
      16, 0, 0);
}

// 32x32x32 fragment conventions (scaled from the verified 16x16x64 layout):
//   A operand: lane l holds row (l&31), k = (l>>5)*16 + e  (16 i8 = v4i)
//   B operand: lane l holds col (l&31), k = (l>>5)*16 + e
//   C/D:       col = lane&31, row = (reg&3) + 8*(reg>>2) + 4*(lane>>5)
// A tile (128 rows x 64 k, 8 KiB i8): off = rb*2048 + ks*1024 + lane*16,
//   lane = khalf*32 + row32  (rb=row/32, ks=k/32, khalf=(k%32)/16)
// B tile (128 cols x 64 k, 4 KiB packed): off = np*2048 + ks*1024 + lane*16
//   + par*8;  np = colfrag>>1, par = colfrag&1 (colfrag = col/32);
//   8-byte group: dword d byte j = u[kk+8d+j] | u[kk+8d+j+4]<<4, u = q+8.
// GEMM: A direct from LDS; B expanded in-reg. Epilogue: C = raw - 8*sa[t].

// ---------------------------------------------------------------------------
// Weight unpack: packed int32 [4096][2048] -> biased nibble-packed 32x32 tiles.
// ---------------------------------------------------------------------------
__global__ __launch_bounds__(256) void unpack_w(const int* __restrict__ wp,
                                                char* __restrict__ wq) {
  const int kc = blockIdx.x;   // 0..63
  const int nt = blockIdx.y;   // 0..31 (128-col units)
  const int tid = threadIdx.x;
  char* tile = wq + ((size_t)nt * 64 + kc) * 4096;
  const int n0 = nt * 128;
#pragma unroll
  for (int gi = 0; gi < 2; ++gi) {
    int g = gi * 256 + tid;        // 0..511: r = g>>2 (col in tile), cc = g&3
    int r = g >> 2, cc = g & 3;
    const v4i* src = (const v4i*)(wp + (size_t)(n0 + r) * 2048 + kc * 32 + cc * 8);
    v4i m0 = src[0], m1 = src[1];  // ints j=0..7 hold k=2j(lo),2j+1(hi)
    unsigned int d0 =
        ((unsigned)m0.x & 15) | (((unsigned)m0.z & 15) << 4) |
        ((((unsigned)m0.x >> 4) & 15) << 8) | ((((unsigned)m0.z >> 4) & 15) << 12) |
        (((unsigned)m0.y & 15) << 16) | (((unsigned)m0.w & 15) << 20) |
        ((((unsigned)m0.y >> 4) & 15) << 24) | ((((unsigned)m0.w >> 4) & 15) << 28);
    unsigned int d1 =
        ((unsigned)m1.x & 15) | (((unsigned)m1.z & 15) << 4) |
        ((((unsigned)m1.x >> 4) & 15) << 8) | ((((unsigned)m1.z >> 4) & 15) << 12) |
        (((unsigned)m1.y & 15) << 16) | (((unsigned)m1.w & 15) << 20) |
        ((((unsigned)m1.y >> 4) & 15) << 24) | ((((unsigned)m1.w >> 4) & 15) << 28);
    d0 ^= 0x88888888u;  // raw nibble v -> v^8 = q+8
    d1 ^= 0x88888888u;
    // ks = cc>>1, khalf = cc&1, np = (r>>6), par = (r>>5)&1
    *(uint2*)(tile + (r >> 6) * 2048 + (cc >> 1) * 1024 +
              ((cc & 1) * 32 + (r & 31)) * 16 + ((r >> 5) & 1) * 8) =
        make_uint2(d0, d1);
  }
}

// ---------------------------------------------------------------------------
// Activation quant: per-row absmax scale, q = clip(rint(x/scale),-8,7),
// signed-i8 32x32-fragment-tiled output + per-token signed sum sa[t].
// ---------------------------------------------------------------------------
__global__ __launch_bounds__(256) void quant_x(const float* __restrict__ x,
                                               char* __restrict__ xq,
                                               float* __restrict__ xs,
                                               int* __restrict__ sa) {
  __shared__ float lmax[4][4];
  __shared__ int lsum[4][4];
  const int tid = threadIdx.x;
  const int w = tid >> 6;        // wave -> k quarter
  const int l = tid & 63;
  const int t0 = blockIdx.x * 4;
  const int row = l >> 4;
  const int t = t0 + row;
  const int sub = l & 15;

  const float* base = x + (size_t)t * 4096 + w * 1024 + sub * 4;
  float4 vals[16];
  float m = 0.0f;
#pragma unroll
  for (int s = 0; s < 16; ++s) {
    vals[s] = *(const float4*)(base + s * 64);
    m = fmaxf(m, fmaxf(fmaxf(fabsf(vals[s].x), fabsf(vals[s].y)),
                       fmaxf(fabsf(vals[s].z), fabsf(vals[s].w))));
  }
#pragma unroll
  for (int d = 1; d < 16; d <<= 1) m = fmaxf(m, __shfl_xor(m, d, 64));
  if (sub == 0) lmax[w][row] = m;
  __syncthreads();
  float rm = fmaxf(fmaxf(lmax[0][row], lmax[1][row]),
                   fmaxf(lmax[2][row], lmax[3][row]));
  float scale = fmaxf(rm / 7.0f, SCALE_EPS);
  if (w == 0 && sub == 0) xs[t] = scale;

  // dst: tile (mt*64 + kc)*8192; within: rb*2048 + ks*1024 + khalf*512
  //      + r32*16 + (k%16);  k-in-tile = sub*4 -> ks=sub>>3, khalf=(sub>>2)&1
  const int mt = t >> 7;
  const int rb = (t & 127) >> 5;
  char* dst0 = xq + (size_t)mt * 64 * 8192 + rb * 2048 + (sub >> 3) * 1024 +
               ((sub >> 2) & 1) * 512 + (t & 31) * 16 + (sub & 3) * 4;

  int isum = 0;
#pragma unroll
  for (int s = 0; s < 16; ++s) {
    float4 v = vals[s];
    int q0 = (int)fminf(fmaxf(rintf(v.x / scale), -8.0f), 7.0f);
    int q1 = (int)fminf(fmaxf(rintf(v.y / scale), -8.0f), 7.0f);
    int q2 = (int)fminf(fmaxf(rintf(v.z / scale), -8.0f), 7.0f);
    int q3 = (int)fminf(fmaxf(rintf(v.w / scale), -8.0f), 7.0f);
    isum += q0 + q1 + q2 + q3;
    unsigned int wd = (unsigned int)(q0 & 255) | ((unsigned int)(q1 & 255) << 8) |
                      ((unsigned int)(q2 & 255) << 16) | ((unsigned int)(q3 & 255) << 24);
    *(unsigned int*)(dst0 + (size_t)(w * 16 + s) * 8192) = wd;
  }
#pragma unroll
  for (int dd = 1; dd < 16; dd <<= 1) isum += __shfl_xor(isum, dd, 64);
  if (sub == 0) lsum[w][row] = isum;
  __syncthreads();
  if (w == 0 && sub == 0)
    sa[t] = lsum[0][row] + lsum[1][row] + lsum[2][row] + lsum[3][row];
}

// ---------------------------------------------------------------------------
// Hybrid GEMM, 256x256 tile, 8 waves (2Mx4N), BK=64, mfma_i32_32x32x32_i8.
// 16 long MFMAs/wave/K-tile (36.6-cyc pipe occupancy each) instead of 32
// short ones: higher instruction ceiling (4404 vs 3944 TOPS) and 2x issue
// slack per instruction for the 2-wave/SIMD schedule.
// A: i8 via LDS (direct operands); B: nibble-packed (2 reads + 2 UNPK/tile).
// Ring-4 x 24K slots, 4-phase rotation, 1 barrier + counted vmcnt(3)/tile.
// ---------------------------------------------------------------------------
__global__ __launch_bounds__(512, 2) void gemm_i8(const char* __restrict__ xq,
                                                  const char* __restrict__ wq,
                                                  const float* __restrict__ xs,
                                                  const int* __restrict__ sa,
                                                  const float* __restrict__ wsc,
                                                  float* __restrict__ out) {
  __shared__ char lds[4][24576];   // A i8 @0 (16K), B packed @16384 (8K)
  const int tid = threadIdx.x;
  const int wid = tid >> 6;
  const int lane = tid & 63;
  const int wm = wid >> 2;         // 0..1 : M half (128 rows)
  const int wn = wid & 3;          // 0..3 : N quarter (64 cols)

  const int bid = blockIdx.x;
  const int wg = (bid & 7) * 64 + (bid >> 3);
  const int by = wg >> 4;          // 0..31
  const int bx = wg & 15;          // 0..15

  const int toff = tid * 16;       // 0..8191
  const char* aSrc0 = xq + (size_t)(2 * by) * 64 * 8192;
  const char* aSrc1 = aSrc0 + 64 * 8192;
  const char* bSrcT = wq + (size_t)(2 * bx + (toff >> 12)) * 262144 + (toff & 4095);
  const int laoff = lane * 16;

  v16i acc[4][2] = {};             // acc[rb][nf], 16 regs each
  v4i fB[2][4];                    // [buf][ks*2+nf]
  v4i aa0, aa1, aa2, aa3;
  v4i pB0, pB1;
  const unsigned MSK = 0x0f0f0f0fu;

#define LO4(w) (int)((unsigned)(w) & MSK)
#define HI4(w) (int)(((unsigned)(w) >> 4) & MSK)
#define UNPK(da, db, p)                                         \
  do {                                                          \
    da = (v4i){LO4((p).x), HI4((p).x), LO4((p).y), HI4((p).y)}; \
    db = (v4i){LO4((p).z), HI4((p).z), LO4((p).w), HI4((p).w)}; \
  } while (0)

#define STAGE3(kt)                                              \
  do {                                                          \
    char* d_ = lds[(kt) & 3];                                   \
    gll16(aSrc0 + (size_t)(kt) * 8192 + toff, d_ + toff);       \
    gll16(aSrc1 + (size_t)(kt) * 8192 + toff, d_ + 8192 + toff);\
    gll16(bSrcT + (size_t)(kt) * 4096, d_ + 16384 + toff);      \
  } while (0)

  // 4 mfma: rows {rb0_, rb0_+1} x cols {nf0, nf1} for k-slice ks
#define MFQ(rb0_, xx, yy, c, ks)                                               \
  do {                                                                         \
    __builtin_amdgcn_s_setprio(1);                                             \
    acc[rb0_][0] = __builtin_amdgcn_mfma_i32_32x32x32_i8(                      \
        xx, fB[c][(ks) * 2], acc[rb0_][0], 0, 0, 0);                           \
    acc[rb0_][1] = __builtin_amdgcn_mfma_i32_32x32x32_i8(                      \
        xx, fB[c][(ks) * 2 + 1], acc[rb0_][1], 0, 0, 0);                       \
    acc[rb0_ + 1][0] = __builtin_amdgcn_mfma_i32_32x32x32_i8(                  \
        yy, fB[c][(ks) * 2], acc[rb0_ + 1][0], 0, 0, 0);                       \
    acc[rb0_ + 1][1] = __builtin_amdgcn_mfma_i32_32x32x32_i8(                  \
        yy, fB[c][(ks) * 2 + 1], acc[rb0_ + 1][1], 0, 0, 0);                   \
    __builtin_amdgcn_s_setprio(0);                                             \
  } while (0)

#define TILE(c, kt, do_stage, do_next, vm)                                   \
  do {                                                                       \
    const char* Aw_ = lds[(kt) & 3] + wm * 8192 + laoff;                     \
    const char* Bn_ = lds[((kt) + 1) & 3] + 16384 + (wn >> 1) * 4096 +       \
                      (wn & 1) * 2048 + laoff;                               \
    const char* An_ = lds[((kt) + 1) & 3] + wm * 8192 + laoff;               \
    /* P0: read A(rb2,ks0),A(rb3,ks0); mfma ks0 rb0,rb1 */                   \
    aa2 = *(const v4i*)(Aw_ + 4096);                                         \
    aa3 = *(const v4i*)(Aw_ + 6144);                                         \
    MFQ(0, aa0, aa1, c, 0);                                                  \
    /* P1: read A(rb0,ks1),A(rb1,ks1); mfma ks0 rb2,rb3 */                   \
    aa0 = *(const v4i*)(Aw_ + 1024);                                         \
    aa1 = *(const v4i*)(Aw_ + 3072);                                         \
    MFQ(2, aa2, aa3, c, 0);                                                  \
    /* mid-tile: certify slot kt+1 (counted), sync */                        \
    if ((vm) == 3) asm volatile("s_waitcnt vmcnt(3)" ::: "memory");          \
    else if ((vm) == 0) asm volatile("s_waitcnt vmcnt(0)" ::: "memory");     \
    __builtin_amdgcn_s_barrier();                                            \
    __builtin_amdgcn_sched_barrier(0);                                       \
    /* P2: stage kt+3; read A(rb2,ks1),A(rb3,ks1) + next-B ks0; ks1 rb0,1 */ \
    if (do_stage) STAGE3((kt) + 3);                                          \
    aa2 = *(const v4i*)(Aw_ + 5120);                                         \
    aa3 = *(const v4i*)(Aw_ + 7168);                                         \
    if (do_next) pB0 = *(const v4i*)(Bn_);                                   \
    MFQ(0, aa0, aa1, c, 1);                                                  \
    /* P3: read next-B ks1 + next-A(rb0,ks0),(rb1,ks0); ks1 rb2,rb3 */       \
    if (do_next) {                                                           \
      pB1 = *(const v4i*)(Bn_ + 1024);                                       \
      aa0 = *(const v4i*)(An_);                                              \
      aa1 = *(const v4i*)(An_ + 2048);                                       \
    }                                                                        \
    MFQ(2, aa2, aa3, c, 1);                                                  \
    if (do_next) {                                                           \
      UNPK(fB[1 - (c)][0], fB[1 - (c)][1], pB0);                             \
      UNPK(fB[1 - (c)][2], fB[1 - (c)][3], pB1);                             \
    }                                                                        \
  } while (0)

  // prologue: stage 0,1,2 (9 loads); certify slot 0; preload B(0) + A rb0,rb1
  STAGE3(0); STAGE3(1); STAGE3(2);
  asm volatile("s_waitcnt vmcnt(6)" ::: "memory");
  __builtin_amdgcn_s_barrier();
  __builtin_amdgcn_sched_barrier(0);
  {
    const char* A0_ = lds[0] + wm * 8192 + laoff;
    const char* B0_ = lds[0] + 16384 + (wn >> 1) * 4096 + (wn & 1) * 2048 + laoff;
    aa0 = *(const v4i*)(A0_);          // rb0 ks0
    aa1 = *(const v4i*)(A0_ + 2048);   // rb1 ks0
    pB0 = *(const v4i*)(B0_);
    pB1 = *(const v4i*)(B0_ + 1024);
    UNPK(fB[0][0], fB[0][1], pB0);
    UNPK(fB[0][2], fB[0][3], pB1);
  }

  for (int kt = 0; kt < 60; kt += 2) {
    TILE(0, kt, 1, 1, 3);
    TILE(1, kt + 1, 1, 1, 3);
  }
  TILE(0, 60, 1, 1, 3);   // stages slot 63 (last)
  TILE(1, 61, 0, 1, 3);   // slot 62 certified (63's 3 loads remain)
  TILE(0, 62, 0, 1, 0);   // slot 63 certified
  TILE(1, 63, 0, 0, -1);  // pure drain

#undef TILE
#undef MFQ
#undef STAGE3
#undef UNPK
#undef LO4
#undef HI4

  // epilogue: C/D 32x32: col = lane&31, row = (reg&3)+8*(reg>>2)+4*(lane>>5)
  float wv0 = wsc[bx * 256 + wn * 64 + (lane & 31)];
  float wv1 = wsc[bx * 256 + wn * 64 + 32 + (lane & 31)];
  const int cb = bx * 256 + wn * 64 + (lane & 31);
  const int rw = by * 256 + wm * 128 + ((lane >> 5) << 2);
#pragma unroll
  for (int rb = 0; rb < 4; ++rb) {
#pragma unroll
    for (int g = 0; g < 4; ++g) {
#pragma unroll
      for (int j = 0; j < 4; ++j) {
        int row = rw + rb * 32 + g * 8 + j;
        int reg = g * 4 + j;
        int sv = sa[row];
        float s = xs[row];
        float* orow = out + (size_t)row * 4096 + cb;
        orow[0]  = (float)(acc[rb][0][reg] - 8 * sv) * (s * wv0);
        orow[32] = (float)(acc[rb][1][reg] - 8 * sv) * (s * wv1);
      }
    }
  }
}

extern "C" void kernel_launch(void* const* d_in, const int* in_sizes, int n_in,
                              void* d_out, int out_size, void* d_ws, size_t ws_size,
                              hipStream_t stream) {
  const float* x = (const float*)d_in[0];
  const int* wp = (const int*)d_in[1];
  const float* wsc = (const float*)d_in[2];
  float* out = (float*)d_out;
  char* ws = (char*)d_ws;

  char* xq = ws;                                   // 8192*4096 i8 = 33554432 B
  char* wq = ws + 33554432;                        // packed 4096*2048 = 8388608 B
  float* xs = (float*)(ws + 41943040);             // 8192*4
  int* sa = (int*)(ws + 41943040 + 32768);         // 8192*4

  hipLaunchKernelGGL(unpack_w, dim3(64, 32), dim3(256), 0, stream, wp, wq);
  hipLaunchKernelGGL(quant_x, dim3(2048), dim3(256), 0, stream, x, xq, xs, sa);
  hipLaunchKernelGGL(gemm_i8, dim3(512), dim3(512), 0, stream, xq, wq, xs, sa, wsc, out);
}

// Round 9
// 164.058 us; speedup vs baseline: 1.0703x; 1.0703x over previous
//
#include <hip/hip_runtime.h>

#define SCALE_EPS 1e-5f

typedef int v4i __attribute__((ext_vector_type(4)));
typedef int v16i __attribute__((ext_vector_type(16)));

static __device__ __forceinline__ void gll16(const void* g, void* l) {
  __builtin_amdgcn_global_load_lds(
      (const __attribute__((address_space(1))) unsigned int*)g,
      (__attribute__((address_space(3))) unsigned int*)l,
      16, 0, 0);
}

// Nibble-pair packed operand format (both A and B), biased u = q+8:
//   packed byte e of a 32x32 k-pair fragment: u[k= kh*16+e'] | u[k+32]<<4
//   fragment lane l = kh*32 + (row_or_col % 32); 16 B/lane -> ds_read_b128
//   yields BOTH ks=0 (lo nibbles) and ks=1 (hi nibbles) v4i MFMA operands.
// A tile (256 rows x 64 k, packed 8 KiB) at xq + (mt*64+kc)*8192:
//   off = rb*1024 + lane*16 + e   (rb = row%256/32)
// B tile (256 cols x 64 k, packed 8 KiB) at wq + (nt*64+kc)*8192:
//   off = cf*1024 + lane*16 + e   (cf = col%256/32)
// Bias removal: C = raw - 8*(sa_signed[t] + swU_biased[o])  (exact).

// ---------------------------------------------------------------------------
// Weight unpack: packed int32 [4096][2048] -> biased nibble-pair tiles.
// ---------------------------------------------------------------------------
__global__ __launch_bounds__(256) void unpack_w(const int* __restrict__ wp,
                                                char* __restrict__ wq) {
  const int kc = blockIdx.x;   // 0..63
  const int nt2 = blockIdx.y;  // 0..15 (256-col tiles)
  const int tid = threadIdx.x;
  char* tile = wq + ((size_t)nt2 * 64 + kc) * 8192;
#pragma unroll
  for (int it = 0; it < 8; ++it) {
    int idx = it * 256 + tid;      // 0..2047
    int c = idx >> 3;              // col in tile 0..255
    int rem = idx & 7;
    int kh = rem >> 2, q = rem & 3;
    // source ints: k_lo = kc*64 + kh*16 + q*4 -> int index kc*32+kh*8+q*2 (+1);
    // hi partners (k_lo+32) at +16.
    const int* src = wp + (size_t)(nt2 * 256 + c) * 2048 + kc * 32 + kh * 8 + q * 2;
    int i0 = src[0], i1 = src[1], j0 = src[16], j1 = src[17];
    unsigned dw = ((unsigned)i0 & 15) | (((unsigned)j0 & 15) << 4) |
                  ((((unsigned)i0 >> 4) & 15) << 8) | ((((unsigned)j0 >> 4) & 15) << 12) |
                  (((unsigned)i1 & 15) << 16) | (((unsigned)j1 & 15) << 20) |
                  ((((unsigned)i1 >> 4) & 15) << 24) | ((((unsigned)j1 >> 4) & 15) << 28);
    dw ^= 0x88888888u;  // raw nibble v -> v^8 = q+8 (biased)
    *(unsigned*)(tile + (c >> 5) * 1024 + (kh * 32 + (c & 31)) * 16 + q * 4) = dw;
  }
}

// ---------------------------------------------------------------------------
// Per-out-feature BIASED nibble sum: swU[o] = sum_k (q_w + 8).
// ---------------------------------------------------------------------------
__global__ __launch_bounds__(256) void sum_w(const int* __restrict__ wp,
                                             int* __restrict__ sw) {
  __shared__ int ls[4];
  const int row = blockIdx.x;
  const int tid = threadIdx.x;
  const v4i* src = (const v4i*)(wp + (size_t)row * 2048 + tid * 8);
  v4i m0 = src[0], m1 = src[1];
  int s = 0;
#pragma unroll
  for (int j = 0; j < 4; ++j) {
    int a = (j == 0) ? m0.x : (j == 1) ? m0.y : (j == 2) ? m0.z : m0.w;
    int b = (j == 0) ? m1.x : (j == 1) ? m1.y : (j == 2) ? m1.z : m1.w;
    s += ((a & 15) ^ 8) + (((a >> 4) & 15) ^ 8) + ((b & 15) ^ 8) + (((b >> 4) & 15) ^ 8);
  }
#pragma unroll
  for (int d = 1; d < 64; d <<= 1) s += __shfl_xor(s, d, 64);
  if ((tid & 63) == 0) ls[tid >> 6] = s;
  __syncthreads();
  if (tid == 0) sw[row] = ls[0] + ls[1] + ls[2] + ls[3];
}

// ---------------------------------------------------------------------------
// Activation quant: per-row absmax scale, q = clip(rint(x/scale),-8,7),
// nibble-pair packed tiles (u = q+8) + per-token SIGNED sum sa[t].
// ---------------------------------------------------------------------------
__global__ __launch_bounds__(256) void quant_x(const float* __restrict__ x,
                                               char* __restrict__ xq,
                                               float* __restrict__ xs,
                                               int* __restrict__ sa) {
  __shared__ float lmax[4][4];
  __shared__ int lsum[4][4];
  const int tid = threadIdx.x;
  const int w = tid >> 6;        // wave -> 16 kc chunk
  const int l = tid & 63;
  const int t0 = blockIdx.x * 4;
  const int row = l >> 4;
  const int t = t0 + row;
  const int sub = l & 15;
  const int kcl = sub >> 3;      // which of 2 kc per s
  const int kh = (sub >> 2) & 1;
  const int j = sub & 3;

  // lane covers, for s=0..7: kc = w*16+s*2+kcl; float4 at k_lo and k_lo+32
  float4 va[8], vb[8];
  float m = 0.0f;
#pragma unroll
  for (int s = 0; s < 8; ++s) {
    int kc = w * 16 + s * 2 + kcl;
    const float* p = x + (size_t)t * 4096 + kc * 64 + kh * 16 + j * 4;
    va[s] = *(const float4*)(p);
    vb[s] = *(const float4*)(p + 32);
    m = fmaxf(m, fmaxf(fmaxf(fabsf(va[s].x), fabsf(va[s].y)),
                       fmaxf(fabsf(va[s].z), fabsf(va[s].w))));
    m = fmaxf(m, fmaxf(fmaxf(fabsf(vb[s].x), fabsf(vb[s].y)),
                       fmaxf(fabsf(vb[s].z), fabsf(vb[s].w))));
  }
#pragma unroll
  for (int d = 1; d < 16; d <<= 1) m = fmaxf(m, __shfl_xor(m, d, 64));
  if (sub == 0) lmax[w][row] = m;
  __syncthreads();
  float rm = fmaxf(fmaxf(lmax[0][row], lmax[1][row]),
                   fmaxf(lmax[2][row], lmax[3][row]));
  float scale = fmaxf(rm / 7.0f, SCALE_EPS);
  if (w == 0 && sub == 0) xs[t] = scale;

  char* dst0 = xq + (size_t)(t >> 8) * 524288 + ((t & 255) >> 5) * 1024 +
               (kh * 32 + (t & 31)) * 16 + j * 4;

  int isum = 0;
#pragma unroll
  for (int s = 0; s < 8; ++s) {
    int kc = w * 16 + s * 2 + kcl;
    int q0 = (int)fminf(fmaxf(rintf(va[s].x / scale), -8.0f), 7.0f);
    int q1 = (int)fminf(fmaxf(rintf(va[s].y / scale), -8.0f), 7.0f);
    int q2 = (int)fminf(fmaxf(rintf(va[s].z / scale), -8.0f), 7.0f);
    int q3 = (int)fminf(fmaxf(rintf(va[s].w / scale), -8.0f), 7.0f);
    int q4 = (int)fminf(fmaxf(rintf(vb[s].x / scale), -8.0f), 7.0f);
    int q5 = (int)fminf(fmaxf(rintf(vb[s].y / scale), -8.0f), 7.0f);
    int q6 = (int)fminf(fmaxf(rintf(vb[s].z / scale), -8.0f), 7.0f);
    int q7 = (int)fminf(fmaxf(rintf(vb[s].w / scale), -8.0f), 7.0f);
    isum += q0 + q1 + q2 + q3 + q4 + q5 + q6 + q7;
    // byte b = (q_b+8) | (q_{b+4}+8)<<4
    unsigned dw = (unsigned)((q0 + 8) | ((q4 + 8) << 4)) |
                  ((unsigned)((q1 + 8) | ((q5 + 8) << 4)) << 8) |
                  ((unsigned)((q2 + 8) | ((q6 + 8) << 4)) << 16) |
                  ((unsigned)((q3 + 8) | ((q7 + 8) << 4)) << 24);
    *(unsigned*)(dst0 + (size_t)kc * 8192) = dw;
  }
#pragma unroll
  for (int dd = 1; dd < 16; dd <<= 1) isum += __shfl_xor(isum, dd, 64);
  if (sub == 0) lsum[w][row] = isum;
  __syncthreads();
  if (w == 0 && sub == 0)
    sa[t] = lsum[0][row] + lsum[1][row] + lsum[2][row] + lsum[3][row];
}

// ---------------------------------------------------------------------------
// Packed-nibble GEMM, 256x256 tile, 8 waves (2Mx4N), BK=64, mfma 32x32x32 i8.
// LDS slot 16 KiB (A-packed 8K @0, B-packed 8K @8192), ring-4 = 64 KiB.
// Per tile per wave: 6 ds_read_b128 (48/CU -> ~576 LDS cyc vs 1171 MFMA cyc),
// 6 UNPK (~60 VALU), 16 MFMA in 4 clusters; 1 barrier + counted vmcnt(2).
// Cross-tile rotation: packed regs for kt+1 read+unpacked during kt's MFMAs.
// Epilogue: C = raw - 8*(sa_signed + swU_biased)  (exact, constants cancel).
// R8 fix: restore TILE(60) (R7 dropped it -> K-tile 61 skipped + tile 63
// computed on stale slot data -> absmax 42).
// ---------------------------------------------------------------------------
__global__ __launch_bounds__(512, 2) void gemm_i8(const char* __restrict__ xq,
                                                  const char* __restrict__ wq,
                                                  const float* __restrict__ xs,
                                                  const int* __restrict__ sa,
                                                  const int* __restrict__ sw,
                                                  const float* __restrict__ wsc,
                                                  float* __restrict__ out) {
  __shared__ char lds[4][16384];
  const int tid = threadIdx.x;
  const int wid = tid >> 6;
  const int lane = tid & 63;
  const int wm = wid >> 2;         // 0..1 : M half (128 rows)
  const int wn = wid & 3;          // 0..3 : N quarter (64 cols)

  const int bid = blockIdx.x;
  const int wg = (bid & 7) * 64 + (bid >> 3);
  const int by = wg >> 4;          // 0..31
  const int bx = wg & 15;          // 0..15

  const int toff = tid * 16;       // 0..8191
  const char* aSrc = xq + (size_t)by * 524288;
  const char* bSrc = wq + (size_t)bx * 524288;
  const int laoff = lane * 16;

  v16i acc[4][2] = {};             // acc[rb][nf]
  v4i pA0, pA1, pA2, pA3, pB0, pB1;                    // packed (next/current)
  v4i a00, a01, a10, a11, a20, a21, a30, a31;          // unpacked A [rb][ks]
  v4i b00, b01, b10, b11;                              // unpacked B [nf][ks]
  const unsigned MSK = 0x0f0f0f0fu;

#define LO4(w) (int)((unsigned)(w) & MSK)
#define HI4(w) (int)(((unsigned)(w) >> 4) & MSK)
#define UNPK(d0, d1, p)                                        \
  do {                                                         \
    d0 = (v4i){LO4((p).x), LO4((p).y), LO4((p).z), LO4((p).w)}; \
    d1 = (v4i){HI4((p).x), HI4((p).y), HI4((p).z), HI4((p).w)}; \
  } while (0)

#define STAGE2(kt)                                             \
  do {                                                         \
    char* d_ = lds[(kt) & 3] + toff;                           \
    gll16(aSrc + (size_t)(kt) * 8192 + toff, d_);              \
    gll16(bSrc + (size_t)(kt) * 8192 + toff, d_ + 8192);       \
  } while (0)

  // 4 mfma: rows {rb, rb+1} x col-frags {0,1}
#define CL(rb, xx, yy, bA, bB)                                                 \
  do {                                                                         \
    __builtin_amdgcn_s_setprio(1);                                             \
    acc[rb][0] = __builtin_amdgcn_mfma_i32_32x32x32_i8(xx, bA, acc[rb][0], 0, 0, 0);   \
    acc[rb][1] = __builtin_amdgcn_mfma_i32_32x32x32_i8(xx, bB, acc[rb][1], 0, 0, 0);   \
    acc[rb + 1][0] = __builtin_amdgcn_mfma_i32_32x32x32_i8(yy, bA, acc[rb + 1][0], 0, 0, 0); \
    acc[rb + 1][1] = __builtin_amdgcn_mfma_i32_32x32x32_i8(yy, bB, acc[rb + 1][1], 0, 0, 0); \
    __builtin_amdgcn_s_setprio(0);                                             \
  } while (0)

#define TILE(kt, do_stage, do_next, vm)                                      \
  do {                                                                       \
    const char* An_ = lds[((kt) + 1) & 3] + wm * 4096 + laoff;               \
    const char* Bn_ = lds[((kt) + 1) & 3] + 8192 + wn * 2048 + laoff;        \
    /* first half: unpack rb2,rb3 (packed held from prev tile); ks0 MFMAs */ \
    UNPK(a20, a21, pA2);                                                     \
    UNPK(a30, a31, pA3);                                                     \
    CL(0, a00, a10, b00, b10);                                               \
    CL(2, a20, a30, b00, b10);                                               \
    /* mid-tile: certify slot kt+1 (counted), sync */                        \
    if ((vm) == 2) asm volatile("s_waitcnt vmcnt(2)" ::: "memory");          \
    else if ((vm) == 0) asm volatile("s_waitcnt vmcnt(0)" ::: "memory");     \
    __builtin_amdgcn_s_barrier();                                            \
    __builtin_amdgcn_sched_barrier(0);                                       \
    /* second half: stage kt+3, read kt+1 packed, ks1 MFMAs, unpack next */  \
    if (do_stage) STAGE2((kt) + 3);                                          \
    if (do_next) {                                                           \
      pA0 = *(const v4i*)(An_);                                              \
      pA1 = *(const v4i*)(An_ + 1024);                                       \
      pB0 = *(const v4i*)(Bn_);                                              \
      pB1 = *(const v4i*)(Bn_ + 1024);                                       \
    }                                                                        \
    CL(0, a01, a11, b01, b11);                                               \
    if (do_next) {                                                           \
      pA2 = *(const v4i*)(An_ + 2048);                                       \
      pA3 = *(const v4i*)(An_ + 3072);                                       \
    }                                                                        \
    CL(2, a21, a31, b01, b11);                                               \
    if (do_next) {                                                           \
      UNPK(a00, a01, pA0);                                                   \
      UNPK(a10, a11, pA1);                                                   \
      UNPK(b00, b01, pB0);                                                   \
      UNPK(b10, b11, pB1);                                                   \
    }                                                                        \
  } while (0)

  // prologue: stage tiles 0,1,2; certify slot 0; read+unpack slot-0 operands
  STAGE2(0); STAGE2(1); STAGE2(2);
  asm volatile("s_waitcnt vmcnt(4)" ::: "memory");
  __builtin_amdgcn_s_barrier();
  __builtin_amdgcn_sched_barrier(0);
  {
    const char* A0_ = lds[0] + wm * 4096 + laoff;
    const char* B0_ = lds[0] + 8192 + wn * 2048 + laoff;
    pA0 = *(const v4i*)(A0_);
    pA1 = *(const v4i*)(A0_ + 1024);
    pA2 = *(const v4i*)(A0_ + 2048);
    pA3 = *(const v4i*)(A0_ + 3072);
    pB0 = *(const v4i*)(B0_);
    pB1 = *(const v4i*)(B0_ + 1024);
    UNPK(a00, a01, pA0);
    UNPK(a10, a11, pA1);
    UNPK(b00, b01, pB0);
    UNPK(b10, b11, pB1);
  }

  for (int kt = 0; kt < 60; kt += 2) {
    TILE(kt, 1, 1, 2);
    TILE(kt + 1, 1, 1, 2);
  }
  TILE(60, 1, 1, 2);   // stages slot 63 (last) — was missing in R7
  TILE(61, 0, 1, 2);
  TILE(62, 0, 1, 0);
  TILE(63, 0, 0, -1);

#undef TILE
#undef CL
#undef STAGE2
#undef UNPK
#undef LO4
#undef HI4

  // epilogue: C/D 32x32: col = lane&31, row = (reg&3)+8*(reg>>2)+4*(lane>>5)
  const int colb = bx * 256 + wn * 64 + (lane & 31);
  int sw0 = sw[colb];
  int sw1 = sw[colb + 32];
  float wv0 = wsc[colb];
  float wv1 = wsc[colb + 32];
  const int rw = by * 256 + wm * 128 + ((lane >> 5) << 2);
#pragma unroll
  for (int rb = 0; rb < 4; ++rb) {
#pragma unroll
    for (int g = 0; g < 4; ++g) {
#pragma unroll
      for (int j = 0; j < 4; ++j) {
        int r = rw + rb * 32 + g * 8 + j;
        int reg = g * 4 + j;
        int sv = sa[r];
        float s = xs[r];
        float* orow = out + (size_t)r * 4096 + colb;
        orow[0]  = (float)(acc[rb][0][reg] - 8 * (sv + sw0)) * (s * wv0);
        orow[32] = (float)(acc[rb][1][reg] - 8 * (sv + sw1)) * (s * wv1);
      }
    }
  }
}

extern "C" void kernel_launch(void* const* d_in, const int* in_sizes, int n_in,
                              void* d_out, int out_size, void* d_ws, size_t ws_size,
                              hipStream_t stream) {
  const float* x = (const float*)d_in[0];
  const int* wp = (const int*)d_in[1];
  const float* wsc = (const float*)d_in[2];
  float* out = (float*)d_out;
  char* ws = (char*)d_ws;

  char* xq = ws;                                   // packed 8192*2048 = 16777216 B
  char* wq = ws + 16777216;                        // packed 4096*2048 =  8388608 B
  float* xs = (float*)(ws + 25165824);             // 8192*4
  int* sa = (int*)(ws + 25165824 + 32768);         // 8192*4
  int* sw = (int*)(ws + 25165824 + 65536);         // 4096*4

  hipLaunchKernelGGL(unpack_w, dim3(64, 16), dim3(256), 0, stream, wp, wq);
  hipLaunchKernelGGL(sum_w, dim3(4096), dim3(256), 0, stream, wp, sw);
  hipLaunchKernelGGL(quant_x, dim3(2048), dim3(256), 0, stream, x, xq, xs, sa);
  hipLaunchKernelGGL(gemm_i8, dim3(512), dim3(512), 0, stream, xq, wq, xs, sa, sw, wsc, out);
}